// Round 5
// baseline (2771.287 us; speedup 1.0000x reference)
//
#include <hip/hip_runtime.h>
#include <math.h>

typedef float v2f __attribute__((ext_vector_type(2)));
typedef float v4f __attribute__((ext_vector_type(4)));

#define NMAT 32768
#define SW1 6          // pass-1 sweeps (cold start)
#define SW2 3          // pass-2 sweeps (warm start)
#define SW_SINGLE 10   // single-matrix eigs
#define SP 34          // padded row stride for single-wave LDS matrices

// workspace float offsets
#define WS_G    0
#define WS_GS   1024
#define WS_GIS  2048
#define WS_GT   3072
#define WS_K    4096
#define WS_C    5120
#define WS_VAR  6144
#define WS_TOTAL 6400

// pair-swizzled 32x32 tile: element (r,c) at r*32 + 2*((c>>1)^(r&15)) + (c&1).
__device__ __forceinline__ int swz(int r, int c) {
    return r * 32 + 2 * ((c >> 1) ^ (r & 15)) + (c & 1);
}

// same-wave LDS write->read visibility (no block barrier needed)
__device__ __forceinline__ void wave_fence() {
    asm volatile("s_waitcnt lgkmcnt(0)" ::: "memory");
}

// ---------------------------------------------------------------------------
// One-sided Jacobi, fast-Givens form, XOR tournament.
// Latency-optimized: early scalar shuffles, 4-chain dots, short rotation
// formula t = sgn(d)*b/(|d|+sqrt(d^2+b^2)) (identical algebra, no selects).
// ---------------------------------------------------------------------------
__device__ __forceinline__ float jacobi_fg(v2f (&v)[16], int col, int sweeps) {
    float dn = 0.f;
    #pragma unroll 1
    for (int sweep = 0; sweep < sweeps; ++sweep) {
        {
            v2f n0 = v[0] * v[0], n1 = v[1] * v[1], n2 = v[2] * v[2], n3 = v[3] * v[3];
            #pragma unroll
            for (int j = 4; j < 16; j += 4) {
                n0 += v[j] * v[j];     n1 += v[j + 1] * v[j + 1];
                n2 += v[j + 2] * v[j + 2]; n3 += v[j + 3] * v[j + 3];
            }
            v2f nt = (n0 + n1) + (n2 + n3);
            dn = nt.x + nt.y;
        }
        float sc = 1.f, rsc = 1.f;
        #pragma unroll 1
        for (int m = 1; m < 32; ++m) {
            const float dnq = __shfl_xor(dn, m, 64);   // issued first: drained
            const float dq  = __shfl_xor(sc, m, 64);   // before o[] completes
            v2f o[16];
            #pragma unroll
            for (int j = 0; j < 16; ++j) {
                o[j].x = __shfl_xor(v[j].x, m, 64);
                o[j].y = __shfl_xor(v[j].y, m, 64);
            }
            v2f p0 = v[0] * o[0], p1 = v[1] * o[1], p2 = v[2] * o[2], p3 = v[3] * o[3];
            #pragma unroll
            for (int j = 4; j < 16; j += 4) {
                p0 += v[j] * o[j];     p1 += v[j + 1] * o[j + 1];
                p2 += v[j + 2] * o[j + 2]; p3 += v[j + 3] * o[j + 3];
            }
            v2f pt = (p0 + p1) + (p2 + p3);
            const float raw = pt.x + pt.y;
            const bool  isp = col < (col ^ m);
            const float apq = (sc * dq) * raw;
            const float b   = apq + apq;
            const float d   = isp ? (dnq - dn) : (dn - dnq);   // aqq - app
            const float r2  = __builtin_fmaf(d, d, b * b);
            const float sr  = __builtin_amdgcn_sqrtf(r2);
            const float u   = fmaxf(fabsf(d) + sr, 1e-30f);
            const float t   = (d < 0.f ? -b : b) * __builtin_amdgcn_rcpf(u);
            const float s1  = __builtin_fmaf(t, t, 1.f);
            const float c   = __builtin_amdgcn_rsqf(s1);
            const float gam = t * (dq * rsc);
            const float gs  = isp ? -gam : gam;
            const v2f gs2 = {gs, gs};
            #pragma unroll
            for (int j = 0; j < 16; ++j) v[j] += gs2 * o[j];
            sc *= c; rsc *= c * s1;                     // c*s1 = 1/c
            dn = __builtin_fmaf(isp ? -t : t, apq, dn);
        }
        const v2f s2 = {sc, sc};
        #pragma unroll
        for (int j = 0; j < 16; ++j) v[j] *= s2;
    }
    v2f n0 = v[0] * v[0], n1 = v[1] * v[1], n2 = v[2] * v[2], n3 = v[3] * v[3];
    #pragma unroll
    for (int j = 4; j < 16; j += 4) {
        n0 += v[j] * v[j];     n1 += v[j + 1] * v[j + 1];
        n2 += v[j + 2] * v[j + 2]; n3 += v[j + 3] * v[j + 3];
    }
    v2f nt = (n0 + n1) + (n2 + n3);
    return nt.x + nt.y;
}

// ---------------------------------------------------------------------------
// Single-wave helpers
// ---------------------------------------------------------------------------
__device__ __forceinline__ void put_col(float* L, const v2f (&w)[16], int col) {
    #pragma unroll
    for (int j = 0; j < 16; ++j) {
        L[(2 * j) * SP + col]     = w[j].x;
        L[(2 * j + 1) * SP + col] = w[j].y;
    }
}

__device__ __forceinline__ void colmm(const float* L, const v2f (&y)[16], v2f (&z)[16]) {
    #pragma unroll
    for (int i = 0; i < 32; ++i) {
        v2f acc = {0.f, 0.f};
        #pragma unroll
        for (int q = 0; q < 16; ++q) {
            v2f mm = *(const v2f*)&L[i * SP + 2 * q];
            acc += mm * y[q];
        }
        float zi = acc.x + acc.y;
        if (i & 1) z[i >> 1].y = zi; else z[i >> 1].x = zi;
    }
}

__device__ __forceinline__ void recon_col(const float* LW, float coef, int col,
                                          int base, v2f (&z)[16]) {
    float rv[32];
    #pragma unroll
    for (int k = 0; k < 32; ++k) rv[k] = LW[col * SP + k];
    v2f y[16];
    #pragma unroll
    for (int q = 0; q < 16; ++q) {
        y[q].x = __shfl(coef, base | (2 * q), 64)     * rv[2 * q];
        y[q].y = __shfl(coef, base | (2 * q + 1), 64) * rv[2 * q + 1];
    }
    colmm(LW, y, z);
}

// ---------------------------------------------------------------------------
// K1: arithmetic mean -> ws[WS_G]
// ---------------------------------------------------------------------------
__global__ __launch_bounds__(256) void k_mean(const float* __restrict__ X,
                                              float* __restrict__ ws) {
    const int t = threadIdx.x;
    const size_t base = (size_t)blockIdx.x * 16 * 1024;
    float4 a = {0.f, 0.f, 0.f, 0.f};
    for (int m = 0; m < 16; ++m) {
        float4 f = *(const float4*)&X[base + (size_t)m * 1024 + t * 4];
        a.x += f.x; a.y += f.y; a.z += f.z; a.w += f.w;
    }
    const float s = 1.0f / (float)NMAT;
    atomicAdd(ws + WS_G + 4 * t + 0, a.x * s);
    atomicAdd(ws + WS_G + 4 * t + 1, a.y * s);
    atomicAdd(ws + WS_G + 4 * t + 2, a.z * s);
    atomicAdd(ws + WS_G + 4 * t + 3, a.w * s);
}

// ---------------------------------------------------------------------------
// K2: block 0: eig(G) -> Gs, Gis.  block 1: eig(B) -> C = B^{1/2} R.
// ---------------------------------------------------------------------------
__global__ __launch_bounds__(64) void k_small_prep(const float* __restrict__ R,
                                                   const float* __restrict__ B,
                                                   float* __restrict__ ws) {
    __shared__ float LW[32 * SP];
    const int lane = threadIdx.x;
    const int col  = lane & 31;
    const int base = lane & 32;
    if (blockIdx.x == 0) {
        v2f w[16];
        #pragma unroll
        for (int j = 0; j < 16; ++j) {
            w[j].x = ws[WS_G + (2 * j) * 32 + col];
            w[j].y = ws[WS_G + (2 * j + 1) * 32 + col];
        }
        const float dn = jacobi_fg(w, col, SW_SINGLE);   // dn = lam^2
        put_col(LW, w, col);
        __syncthreads();
        const float lam = __builtin_amdgcn_sqrtf(dn);
        const float cs  = __builtin_amdgcn_sqrtf(lam) * __builtin_amdgcn_rcpf(dn);
        const float cis = __builtin_amdgcn_rsqf(lam)  * __builtin_amdgcn_rcpf(dn);
        v2f z[16];
        recon_col(LW, cs, col, base, z);    // Gs
        #pragma unroll
        for (int j = 0; j < 16; ++j) {
            ws[WS_GS + (2 * j) * 32 + col]     = z[j].x;
            ws[WS_GS + (2 * j + 1) * 32 + col] = z[j].y;
        }
        recon_col(LW, cis, col, base, z);   // Gis
        #pragma unroll
        for (int j = 0; j < 16; ++j) {
            ws[WS_GIS + (2 * j) * 32 + col]     = z[j].x;
            ws[WS_GIS + (2 * j + 1) * 32 + col] = z[j].y;
        }
    } else {
        v2f w[16];
        #pragma unroll
        for (int j = 0; j < 16; ++j) {
            w[j].x = B[(2 * j) * 32 + col];
            w[j].y = B[(2 * j + 1) * 32 + col];
        }
        const float dn = jacobi_fg(w, col, SW_SINGLE);
        put_col(LW, w, col);
        __syncthreads();
        const float lam = __builtin_amdgcn_sqrtf(dn);
        const float cbs = __builtin_amdgcn_sqrtf(lam) * __builtin_amdgcn_rcpf(dn);
        v2f bs[16];
        recon_col(LW, cbs, col, base, bs);  // Bs = B^{1/2}
        __syncthreads();
        put_col(LW, bs, col);               // LW <- Bs
        __syncthreads();
        v2f r[16];
        #pragma unroll
        for (int j = 0; j < 16; ++j) {
            r[j].x = R[(2 * j) * 32 + col];
            r[j].y = R[(2 * j + 1) * 32 + col];
        }
        v2f c[16];
        colmm(LW, r, c);                    // C = Bs * R
        #pragma unroll
        for (int j = 0; j < 16; ++j) {
            ws[WS_C + (2 * j) * 32 + col]     = c[j].x;
            ws[WS_C + (2 * j + 1) * 32 + col] = c[j].y;
        }
    }
}

// ---------------------------------------------------------------------------
// K3 (pass 1): M = Gis X Gis (X rows broadcast from GLOBAL; only Gis in LDS);
// fast-Givens Jacobi; W1 -> w1out.
// ---------------------------------------------------------------------------
__global__ __launch_bounds__(256, 6) void k_batch_log(const float* __restrict__ X,
                                                      float* __restrict__ w1out,
                                                      const float* __restrict__ ws) {
    __shared__ float HL[1024];       // Gis, pair-swizzled
    const int tid = threadIdx.x;
    for (int e = tid; e < 1024; e += 256) {
        int r = e >> 5, c = e & 31;
        HL[swz(r, c)] = ws[WS_GIS + e];
    }
    __syncthreads();

    const int lane = tid & 63;
    const int col  = lane & 31;
    const int matl = (tid >> 6) * 2 + (lane >> 5);
    const size_t gm = (size_t)blockIdx.x * 8 + matl;
    const float* Xm = X + gm * 1024;
    const int cm = col & 15, cbase = col * 32;

    v2f h2[16];
    #pragma unroll
    for (int p = 0; p < 16; ++p) h2[p] = *(const v2f*)&HL[cbase + 2 * (p ^ cm)];

    v2f t2[16];
    #pragma unroll
    for (int i = 0; i < 32; ++i) {
        const float4* row = (const float4*)(Xm + i * 32);
        v2f acc = {0.f, 0.f};
        #pragma unroll
        for (int q = 0; q < 8; ++q) {
            float4 f = row[q];
            v2f lo = {f.x, f.y}, hi = {f.z, f.w};
            acc += lo * h2[2 * q] + hi * h2[2 * q + 1];
        }
        float ti = acc.x + acc.y;
        if (i & 1) t2[i >> 1].y = ti; else t2[i >> 1].x = ti;
    }
    v2f v[16];
    #pragma unroll
    for (int i = 0; i < 32; ++i) {
        v2f acc = {0.f, 0.f};
        const int tw = i & 15;
        #pragma unroll
        for (int q = 0; q < 8; ++q) {
            v4f f = *(const v4f*)&HL[i * 32 + 4 * q];
            v2f lo = {f.x, f.y}, hi = {f.z, f.w};
            acc += lo * t2[(2 * q) ^ tw] + hi * t2[(2 * q + 1) ^ tw];
        }
        float wi = acc.x + acc.y;
        if (i & 1) v[i >> 1].y = wi; else v[i >> 1].x = wi;
    }

    jacobi_fg(v, col, SW1);

    float* outp = w1out + gm * 1024 + col;
    #pragma unroll
    for (int j = 0; j < 16; ++j) {
        outp[(2 * j) * 32]     = v[j].x;
        outp[(2 * j + 1) * 32] = v[j].y;
    }
}

// ---------------------------------------------------------------------------
// K3b: GT += mean_m W diag(log(lam)/lam^2) W^T. Per-wave 4KB take-turns tile,
// half-waves split recon rows; block ACC only for final global atomics.
// ---------------------------------------------------------------------------
__global__ __launch_bounds__(256, 6) void k_gt(const float* __restrict__ w1,
                                               float* __restrict__ ws) {
    __shared__ float TW[4][1024];
    __shared__ float GB[4][2][32];
    __shared__ float ACC[1024];
    const int tid  = threadIdx.x;
    const int lane = tid & 63;
    const int col  = lane & 31;
    const int half = lane >> 5;
    const int wv   = tid >> 6;
    const size_t gm = (size_t)blockIdx.x * 8 + wv * 2 + half;
    const int cm = col & 15, cbase = col * 32;
    float* tw = TW[wv];

    for (int e = tid; e < 1024; e += 256) ACC[e] = 0.f;
    __syncthreads();

    // own column of own matrix (row-coalesced across lanes)
    const float* wp = w1 + gm * 1024 + col;
    float w[32];
    #pragma unroll
    for (int i = 0; i < 32; ++i) w[i] = wp[i * 32];
    float dn = 0.f;
    #pragma unroll
    for (int i = 0; i < 32; ++i) dn = __builtin_fmaf(w[i], w[i], dn);
    const float g = 0.5f * logf(dn) * __builtin_amdgcn_rcpf(dn) * (1.0f / (float)NMAT);

    float accR[16];
    #pragma unroll
    for (int i = 0; i < 16; ++i) accR[i] = 0.f;

    #pragma unroll 1
    for (int mm = 0; mm < 2; ++mm) {
        if (half == mm) {
            #pragma unroll
            for (int j = 0; j < 16; ++j) {
                tw[swz(2 * j, col)]     = w[2 * j];
                tw[swz(2 * j + 1, col)] = w[2 * j + 1];
            }
            GB[wv][mm][col] = g;
        }
        wave_fence();
        v2f gr[16];
        #pragma unroll
        for (int p2 = 0; p2 < 16; ++p2) {
            v2f wr = *(const v2f*)&tw[cbase + 2 * (p2 ^ cm)];
            v2f gg = *(const v2f*)&GB[wv][mm][2 * p2];
            gr[p2] = gg * wr;
        }
        #pragma unroll
        for (int i = 0; i < 16; ++i) {
            const int r = half * 16 + i;
            const int rw = r & 15;
            v2f acc = {0.f, 0.f};
            #pragma unroll
            for (int q = 0; q < 8; ++q) {
                v4f f = *(const v4f*)&tw[r * 32 + 4 * q];
                v2f lo = {f.x, f.y}, hi = {f.z, f.w};
                acc += lo * gr[(2 * q) ^ rw] + hi * gr[(2 * q + 1) ^ rw];
            }
            accR[i] += acc.x + acc.y;
        }
        wave_fence();   // drain reads before the other half re-stages
    }
    #pragma unroll
    for (int i = 0; i < 16; ++i)
        atomicAdd(&ACC[(half * 16 + i) * 32 + col], accR[i]);
    __syncthreads();
    for (int e = tid; e < 1024; e += 256) atomicAdd(ws + WS_GT + e, ACC[e]);
}

// ---------------------------------------------------------------------------
// K4: E = exp(GT); Gn = Gs E Gs; Gh = Gn^{-1/2}; K = Gh*Gs -> ws[WS_K].
// ---------------------------------------------------------------------------
__global__ __launch_bounds__(64) void k_karcher(float* __restrict__ ws) {
    __shared__ float LA[32 * SP];
    __shared__ float LB[32 * SP];
    const int lane = threadIdx.x;
    const int col  = lane & 31;
    const int base = lane & 32;

    for (int e = lane; e < 1024; e += 64)
        LB[(e >> 5) * SP + (e & 31)] = ws[WS_GS + e];
    v2f gsc[16];
    #pragma unroll
    for (int j = 0; j < 16; ++j) {
        gsc[j].x = ws[WS_GS + (2 * j) * 32 + col];
        gsc[j].y = ws[WS_GS + (2 * j + 1) * 32 + col];
    }
    v2f w[16];
    #pragma unroll
    for (int j = 0; j < 16; ++j) {
        w[j].x = ws[WS_GT + (2 * j) * 32 + col];
        w[j].y = ws[WS_GT + (2 * j + 1) * 32 + col];
    }
    v2f cn2 = {0.f, 0.f};
    #pragma unroll
    for (int j = 0; j < 16; ++j) cn2 += w[j] * w[j];
    float fro2 = cn2.x + cn2.y;
    #pragma unroll
    for (int m = 16; m >= 1; m >>= 1) fro2 += __shfl_xor(fro2, m, 64);
    const float shift = __builtin_amdgcn_sqrtf(fro2) + 0.01f;
    #pragma unroll
    for (int j = 0; j < 16; ++j) {
        w[j].x += (2 * j     == col) ? shift : 0.f;
        w[j].y += (2 * j + 1 == col) ? shift : 0.f;
    }
    const float dn = jacobi_fg(w, col, SW_SINGLE);
    put_col(LA, w, col);
    __syncthreads();
    const float lam = __builtin_amdgcn_sqrtf(dn) - shift;
    const float ce  = expf(lam) * __builtin_amdgcn_rcpf(dn);
    v2f ec[16];
    recon_col(LA, ce, col, base, ec);
    __syncthreads();
    put_col(LA, ec, col);
    __syncthreads();
    v2f u[16], gn[16];
    colmm(LA, gsc, u);
    colmm(LB, u, gn);
    const float dn2 = jacobi_fg(gn, col, SW_SINGLE);
    __syncthreads();
    put_col(LA, gn, col);
    __syncthreads();
    const float lam2 = __builtin_amdgcn_sqrtf(dn2);
    const float ch   = __builtin_amdgcn_rsqf(lam2) * __builtin_amdgcn_rcpf(dn2);
    v2f gh[16];
    recon_col(LA, ch, col, base, gh);
    __syncthreads();
    put_col(LA, gh, col);
    __syncthreads();
    v2f kc[16];
    colmm(LA, gsc, kc);
    #pragma unroll
    for (int j = 0; j < 16; ++j) {
        ws[WS_K + (2 * j) * 32 + col]     = kc[j].x;
        ws[WS_K + (2 * j + 1) * 32 + col] = kc[j].y;
    }
}

// ---------------------------------------------------------------------------
// K5 (pass 2, warm): F = K * W1 * diag(lam1^{-1/2}); 3-sweep Jacobi;
// var += sum(log lam)^2; W2 -> wbuf. lam_k = ||f_k||^2.
// ---------------------------------------------------------------------------
__global__ __launch_bounds__(256, 6) void k_batch_warm(float* __restrict__ wbuf,
                                                       float* __restrict__ ws) {
    __shared__ float KL[1024];
    __shared__ float VARB;
    const int tid = threadIdx.x;
    if (tid == 0) VARB = 0.f;
    for (int e = tid; e < 1024; e += 256) KL[e] = ws[WS_K + e];
    __syncthreads();

    const int lane = tid & 63;
    const int col  = lane & 31;
    const int matl = (tid >> 6) * 2 + (lane >> 5);
    const size_t gm = (size_t)blockIdx.x * 8 + matl;
    float* wp = wbuf + gm * 1024 + col;

    float w1[32];
    #pragma unroll
    for (int i = 0; i < 32; ++i) w1[i] = wp[i * 32];
    float nn = 0.f;
    #pragma unroll
    for (int i = 0; i < 32; ++i) nn = __builtin_fmaf(w1[i], w1[i], nn);
    const float s = __builtin_amdgcn_rsqf(__builtin_amdgcn_sqrtf(nn));
    v2f w1s[16];
    #pragma unroll
    for (int j = 0; j < 16; ++j) { w1s[j].x = w1[2 * j] * s; w1s[j].y = w1[2 * j + 1] * s; }

    v2f v[16];
    #pragma unroll
    for (int i = 0; i < 32; ++i) {
        v2f acc = {0.f, 0.f};
        #pragma unroll
        for (int q = 0; q < 8; ++q) {
            v4f f = *(const v4f*)&KL[i * 32 + 4 * q];
            v2f lo = {f.x, f.y}, hi = {f.z, f.w};
            acc += lo * w1s[2 * q] + hi * w1s[2 * q + 1];
        }
        float fi = acc.x + acc.y;
        if (i & 1) v[i >> 1].y = fi; else v[i >> 1].x = fi;
    }

    const float dn = jacobi_fg(v, col, SW2);   // = lambda (factor init)
    const float lg = logf(dn);
    float contrib = lg * lg;
    #pragma unroll
    for (int m = 32; m >= 1; m >>= 1) contrib += __shfl_xor(contrib, m, 64);
    if (lane == 0) atomicAdd(&VARB, contrib);

    #pragma unroll
    for (int j = 0; j < 16; ++j) {
        wp[(2 * j) * 32]     = v[j].x;
        wp[(2 * j + 1) * 32] = v[j].y;
    }
    __syncthreads();
    if (tid == 0) atomicAdd(ws + WS_VAR, VARB * (1.0f / (float)NMAT));
}

// ---------------------------------------------------------------------------
// K6: p = sqrt(1/(var+eps)); Y = C W2 diag(lam^{(p-1)/2}); out = Y Y^T.
// Per-wave take-turns tile; half-waves split output rows.
// ---------------------------------------------------------------------------
__global__ __launch_bounds__(256, 5) void k_final(float* __restrict__ out,
                                                  const float* __restrict__ ws) {
    __shared__ float CL[1024];
    __shared__ float TW[4][1024];
    const int tid = threadIdx.x;
    for (int e = tid; e < 1024; e += 256) CL[e] = ws[WS_C + e];
    __syncthreads();

    const int lane = tid & 63;
    const int col  = lane & 31;
    const int half = lane >> 5;
    const int wv   = tid >> 6;
    const size_t gmbase = (size_t)blockIdx.x * 8 + wv * 2;
    const size_t gm = gmbase + half;
    const int cm = col & 15, cbase = col * 32;
    float* tw = TW[wv];

    const float var = ws[WS_VAR];
    const float p = sqrtf(1.0f / (var + 1e-5f));

    float w[32];
    #pragma unroll
    for (int i = 0; i < 32; ++i) w[i] = out[gm * 1024 + i * 32 + col];
    float d2 = 0.f;
    #pragma unroll
    for (int i = 0; i < 32; ++i) d2 = __builtin_fmaf(w[i], w[i], d2);
    const float dj = exp2f(log2f(d2) * 0.5f * (p - 1.0f));

    v2f wv2[16];
    #pragma unroll
    for (int j = 0; j < 16; ++j) { wv2[j].x = w[2 * j] * dj; wv2[j].y = w[2 * j + 1] * dj; }

    float y[32];
    #pragma unroll
    for (int i = 0; i < 32; ++i) {
        v2f acc = {0.f, 0.f};
        #pragma unroll
        for (int q = 0; q < 8; ++q) {
            v4f f = *(const v4f*)&CL[i * 32 + 4 * q];
            v2f lo = {f.x, f.y}, hi = {f.z, f.w};
            acc += lo * wv2[2 * q] + hi * wv2[2 * q + 1];
        }
        y[i] = acc.x + acc.y;
    }

    #pragma unroll 1
    for (int mm = 0; mm < 2; ++mm) {
        if (half == mm) {
            #pragma unroll
            for (int j = 0; j < 16; ++j) {
                tw[swz(2 * j, col)]     = y[2 * j];
                tw[swz(2 * j + 1, col)] = y[2 * j + 1];
            }
        }
        wave_fence();
        v2f yc[16];
        #pragma unroll
        for (int p2 = 0; p2 < 16; ++p2)
            yc[p2] = *(const v2f*)&tw[cbase + 2 * (p2 ^ cm)];
        const size_t gmo = gmbase + mm;
        #pragma unroll
        for (int i = 0; i < 16; ++i) {
            const int r = half * 16 + i;
            const int rw = r & 15;
            v2f acc = {0.f, 0.f};
            #pragma unroll
            for (int q = 0; q < 8; ++q) {
                v4f f = *(const v4f*)&tw[r * 32 + 4 * q];
                v2f lo = {f.x, f.y}, hi = {f.z, f.w};
                acc += lo * yc[(2 * q) ^ rw] + hi * yc[(2 * q + 1) ^ rw];
            }
            out[gmo * 1024 + r * 32 + col] = acc.x + acc.y;
        }
        wave_fence();
    }
}

extern "C" void kernel_launch(void* const* d_in, const int* in_sizes, int n_in,
                              void* d_out, int out_size, void* d_ws, size_t ws_size,
                              hipStream_t stream) {
    const float* X = (const float*)d_in[0];
    const float* R = (const float*)d_in[1];
    const float* B = (const float*)d_in[2];
    float* out = (float*)d_out;
    float* ws  = (float*)d_ws;

    hipMemsetAsync(d_ws, 0, WS_TOTAL * sizeof(float), stream);
    k_mean<<<NMAT / 16, 256, 0, stream>>>(X, ws);
    k_small_prep<<<2, 64, 0, stream>>>(R, B, ws);
    k_batch_log<<<NMAT / 8, 256, 0, stream>>>(X, out, ws);
    k_gt<<<NMAT / 8, 256, 0, stream>>>(out, ws);
    k_karcher<<<1, 64, 0, stream>>>(ws);
    k_batch_warm<<<NMAT / 8, 256, 0, stream>>>(out, ws);
    k_final<<<NMAT / 8, 256, 0, stream>>>(out, ws);
}

// Round 6
// 2129.406 us; speedup vs baseline: 1.3014x; 1.3014x over previous
//
#include <hip/hip_runtime.h>
#include <math.h>

typedef float v2f __attribute__((ext_vector_type(2)));
typedef float v4f __attribute__((ext_vector_type(4)));

#define NMAT 32768
#define SW1 4          // pass-1 sweeps (GT averages; pass-2 re-converges)
#define SW2 3          // pass-2 sweeps (warm start)
#define SW_SINGLE 10   // single-matrix eigs
#define SP 34          // padded row stride for single-wave LDS matrices

// workspace float offsets
#define WS_G    0
#define WS_GS   1024
#define WS_GIS  2048
#define WS_GT   3072
#define WS_K    4096
#define WS_C    5120
#define WS_VAR  6144
#define WS_TOTAL 6400

// pair-swizzled 32x32 tile: element (r,c) at r*32 + 2*((c>>1)^(r&15)) + (c&1).
__device__ __forceinline__ int swz(int r, int c) {
    return r * 32 + 2 * ((c >> 1) ^ (r & 15)) + (c & 1);
}

// same-wave LDS write->read visibility (no block barrier needed)
__device__ __forceinline__ void wave_fence() {
    asm volatile("s_waitcnt lgkmcnt(0)" ::: "memory");
}

// ---------------------------------------------------------------------------
// One-sided Jacobi, fast-Givens form, XOR tournament.
// Lane owns one column in 16 v2f regs. Returns final true squared norm.
// ---------------------------------------------------------------------------
__device__ __forceinline__ float jacobi_fg(v2f (&v)[16], int col, int sweeps) {
    float dn = 0.f;
    #pragma unroll 1
    for (int sweep = 0; sweep < sweeps; ++sweep) {
        {
            v2f n0 = v[0] * v[0], n1 = v[1] * v[1], n2 = v[2] * v[2], n3 = v[3] * v[3];
            #pragma unroll
            for (int j = 4; j < 16; j += 4) {
                n0 += v[j] * v[j];     n1 += v[j + 1] * v[j + 1];
                n2 += v[j + 2] * v[j + 2]; n3 += v[j + 3] * v[j + 3];
            }
            v2f nt = (n0 + n1) + (n2 + n3);
            dn = nt.x + nt.y;
        }
        float sc = 1.f, rsc = 1.f;
        #pragma unroll 1
        for (int m = 1; m < 32; ++m) {
            const float dnq = __shfl_xor(dn, m, 64);
            const float dq  = __shfl_xor(sc, m, 64);
            v2f o[16];
            #pragma unroll
            for (int j = 0; j < 16; ++j) {
                o[j].x = __shfl_xor(v[j].x, m, 64);
                o[j].y = __shfl_xor(v[j].y, m, 64);
            }
            v2f p0 = v[0] * o[0], p1 = v[1] * o[1], p2 = v[2] * o[2], p3 = v[3] * o[3];
            #pragma unroll
            for (int j = 4; j < 16; j += 4) {
                p0 += v[j] * o[j];     p1 += v[j + 1] * o[j + 1];
                p2 += v[j + 2] * o[j + 2]; p3 += v[j + 3] * o[j + 3];
            }
            v2f pt = (p0 + p1) + (p2 + p3);
            const float raw = pt.x + pt.y;
            const bool  isp = col < (col ^ m);
            const float apq = (sc * dq) * raw;
            const float b   = apq + apq;
            const float d   = isp ? (dnq - dn) : (dn - dnq);   // aqq - app
            const float r2  = __builtin_fmaf(d, d, b * b);
            const float sr  = __builtin_amdgcn_sqrtf(r2);
            const float u   = fmaxf(fabsf(d) + sr, 1e-30f);
            const float t   = (d < 0.f ? -b : b) * __builtin_amdgcn_rcpf(u);
            const float s1  = __builtin_fmaf(t, t, 1.f);
            const float c   = __builtin_amdgcn_rsqf(s1);
            const float gam = t * (dq * rsc);
            const float gs  = isp ? -gam : gam;
            const v2f gs2 = {gs, gs};
            #pragma unroll
            for (int j = 0; j < 16; ++j) v[j] += gs2 * o[j];
            sc *= c; rsc *= c * s1;                     // c*s1 = 1/c
            dn = __builtin_fmaf(isp ? -t : t, apq, dn);
        }
        const v2f s2 = {sc, sc};
        #pragma unroll
        for (int j = 0; j < 16; ++j) v[j] *= s2;
    }
    v2f n0 = v[0] * v[0], n1 = v[1] * v[1], n2 = v[2] * v[2], n3 = v[3] * v[3];
    #pragma unroll
    for (int j = 4; j < 16; j += 4) {
        n0 += v[j] * v[j];     n1 += v[j + 1] * v[j + 1];
        n2 += v[j + 2] * v[j + 2]; n3 += v[j + 3] * v[j + 3];
    }
    v2f nt = (n0 + n1) + (n2 + n3);
    return nt.x + nt.y;
}

// ---------------------------------------------------------------------------
// Single-wave helpers
// ---------------------------------------------------------------------------
__device__ __forceinline__ void put_col(float* L, const v2f (&w)[16], int col) {
    #pragma unroll
    for (int j = 0; j < 16; ++j) {
        L[(2 * j) * SP + col]     = w[j].x;
        L[(2 * j + 1) * SP + col] = w[j].y;
    }
}

__device__ __forceinline__ void colmm(const float* L, const v2f (&y)[16], v2f (&z)[16]) {
    #pragma unroll
    for (int i = 0; i < 32; ++i) {
        v2f acc = {0.f, 0.f};
        #pragma unroll
        for (int q = 0; q < 16; ++q) {
            v2f mm = *(const v2f*)&L[i * SP + 2 * q];
            acc += mm * y[q];
        }
        float zi = acc.x + acc.y;
        if (i & 1) z[i >> 1].y = zi; else z[i >> 1].x = zi;
    }
}

__device__ __forceinline__ void recon_col(const float* LW, float coef, int col,
                                          int base, v2f (&z)[16]) {
    float rv[32];
    #pragma unroll
    for (int k = 0; k < 32; ++k) rv[k] = LW[col * SP + k];
    v2f y[16];
    #pragma unroll
    for (int q = 0; q < 16; ++q) {
        y[q].x = __shfl(coef, base | (2 * q), 64)     * rv[2 * q];
        y[q].y = __shfl(coef, base | (2 * q + 1), 64) * rv[2 * q + 1];
    }
    colmm(LW, y, z);
}

// ---------------------------------------------------------------------------
// K1: arithmetic mean -> ws[WS_G]
// ---------------------------------------------------------------------------
__global__ __launch_bounds__(256) void k_mean(const float* __restrict__ X,
                                              float* __restrict__ ws) {
    const int t = threadIdx.x;
    const size_t base = (size_t)blockIdx.x * 64 * 1024;
    float4 a = {0.f, 0.f, 0.f, 0.f};
    for (int m = 0; m < 64; ++m) {
        float4 f = *(const float4*)&X[base + (size_t)m * 1024 + t * 4];
        a.x += f.x; a.y += f.y; a.z += f.z; a.w += f.w;
    }
    const float s = 1.0f / (float)NMAT;
    atomicAdd(ws + WS_G + 4 * t + 0, a.x * s);
    atomicAdd(ws + WS_G + 4 * t + 1, a.y * s);
    atomicAdd(ws + WS_G + 4 * t + 2, a.z * s);
    atomicAdd(ws + WS_G + 4 * t + 3, a.w * s);
}

// ---------------------------------------------------------------------------
// K2: block 0: eig(G) -> Gs, Gis.  block 1: eig(B) -> C = B^{1/2} R.
// ---------------------------------------------------------------------------
__global__ __launch_bounds__(64) void k_small_prep(const float* __restrict__ R,
                                                   const float* __restrict__ B,
                                                   float* __restrict__ ws) {
    __shared__ float LW[32 * SP];
    const int lane = threadIdx.x;
    const int col  = lane & 31;
    const int base = lane & 32;
    if (blockIdx.x == 0) {
        v2f w[16];
        #pragma unroll
        for (int j = 0; j < 16; ++j) {
            w[j].x = ws[WS_G + (2 * j) * 32 + col];
            w[j].y = ws[WS_G + (2 * j + 1) * 32 + col];
        }
        const float dn = jacobi_fg(w, col, SW_SINGLE);   // dn = lam^2
        put_col(LW, w, col);
        __syncthreads();
        const float lam = __builtin_amdgcn_sqrtf(dn);
        const float cs  = __builtin_amdgcn_sqrtf(lam) * __builtin_amdgcn_rcpf(dn);
        const float cis = __builtin_amdgcn_rsqf(lam)  * __builtin_amdgcn_rcpf(dn);
        v2f z[16];
        recon_col(LW, cs, col, base, z);    // Gs
        #pragma unroll
        for (int j = 0; j < 16; ++j) {
            ws[WS_GS + (2 * j) * 32 + col]     = z[j].x;
            ws[WS_GS + (2 * j + 1) * 32 + col] = z[j].y;
        }
        recon_col(LW, cis, col, base, z);   // Gis
        #pragma unroll
        for (int j = 0; j < 16; ++j) {
            ws[WS_GIS + (2 * j) * 32 + col]     = z[j].x;
            ws[WS_GIS + (2 * j + 1) * 32 + col] = z[j].y;
        }
    } else {
        v2f w[16];
        #pragma unroll
        for (int j = 0; j < 16; ++j) {
            w[j].x = B[(2 * j) * 32 + col];
            w[j].y = B[(2 * j + 1) * 32 + col];
        }
        const float dn = jacobi_fg(w, col, SW_SINGLE);
        put_col(LW, w, col);
        __syncthreads();
        const float lam = __builtin_amdgcn_sqrtf(dn);
        const float cbs = __builtin_amdgcn_sqrtf(lam) * __builtin_amdgcn_rcpf(dn);
        v2f bs[16];
        recon_col(LW, cbs, col, base, bs);  // Bs = B^{1/2}
        __syncthreads();
        put_col(LW, bs, col);               // LW <- Bs
        __syncthreads();
        v2f r[16];
        #pragma unroll
        for (int j = 0; j < 16; ++j) {
            r[j].x = R[(2 * j) * 32 + col];
            r[j].y = R[(2 * j + 1) * 32 + col];
        }
        v2f c[16];
        colmm(LW, r, c);                    // C = Bs * R
        #pragma unroll
        for (int j = 0; j < 16; ++j) {
            ws[WS_C + (2 * j) * 32 + col]     = c[j].x;
            ws[WS_C + (2 * j + 1) * 32 + col] = c[j].y;
        }
    }
}

// ---------------------------------------------------------------------------
// K3 (pass 1, fused): M = Gis X Gis; fast-Givens Jacobi; W1 -> w1out;
// GT += mean_m W diag(log(lam)/lam^2) W^T  (take-turns per-wave tile).
// ---------------------------------------------------------------------------
__global__ __launch_bounds__(256, 6) void k_batch_log(const float* __restrict__ X,
                                                      float* __restrict__ w1out,
                                                      float* __restrict__ ws) {
    __shared__ float HL[1024];       // Gis, pair-swizzled
    __shared__ float TW[4][1024];    // per-wave take-turns W tile
    __shared__ float GB[4][2][32];   // per-wave, per-half g coefficients
    __shared__ float ACC[1024];      // block GT accumulator
    const int tid = threadIdx.x;
    for (int e = tid; e < 1024; e += 256) {
        int r = e >> 5, c = e & 31;
        HL[swz(r, c)] = ws[WS_GIS + e];
        ACC[e] = 0.f;
    }
    __syncthreads();

    const int lane = tid & 63;
    const int col  = lane & 31;
    const int half = lane >> 5;
    const int wv   = tid >> 6;
    const size_t gm = (size_t)blockIdx.x * 8 + wv * 2 + half;
    const float* Xm = X + gm * 1024;
    const int cm = col & 15, cbase = col * 32;
    float* tw = TW[wv];

    v2f h2[16];
    #pragma unroll
    for (int p = 0; p < 16; ++p) h2[p] = *(const v2f*)&HL[cbase + 2 * (p ^ cm)];

    v2f t2[16];
    #pragma unroll
    for (int i = 0; i < 32; ++i) {
        const float4* row = (const float4*)(Xm + i * 32);
        v2f acc = {0.f, 0.f};
        #pragma unroll
        for (int q = 0; q < 8; ++q) {
            float4 f = row[q];
            v2f lo = {f.x, f.y}, hi = {f.z, f.w};
            acc += lo * h2[2 * q] + hi * h2[2 * q + 1];
        }
        float ti = acc.x + acc.y;
        if (i & 1) t2[i >> 1].y = ti; else t2[i >> 1].x = ti;
    }
    v2f v[16];
    #pragma unroll
    for (int i = 0; i < 32; ++i) {
        v2f acc = {0.f, 0.f};
        const int twi = i & 15;
        #pragma unroll
        for (int q = 0; q < 8; ++q) {
            v4f f = *(const v4f*)&HL[i * 32 + 4 * q];
            v2f lo = {f.x, f.y}, hi = {f.z, f.w};
            acc += lo * t2[(2 * q) ^ twi] + hi * t2[(2 * q + 1) ^ twi];
        }
        float wi = acc.x + acc.y;
        if (i & 1) v[i >> 1].y = wi; else v[i >> 1].x = wi;
    }

    const float dn = jacobi_fg(v, col, SW1);

    // W1 to global (warm-start for pass 2)
    float* outp = w1out + gm * 1024 + col;
    #pragma unroll
    for (int j = 0; j < 16; ++j) {
        outp[(2 * j) * 32]     = v[j].x;
        outp[(2 * j + 1) * 32] = v[j].y;
    }

    // fused GT accumulation: g = log(lam)/lam^2 / N, lam^2 = dn
    const float g = 0.5f * logf(dn) * __builtin_amdgcn_rcpf(dn) * (1.0f / (float)NMAT);

    float accR[16];
    #pragma unroll
    for (int i = 0; i < 16; ++i) accR[i] = 0.f;

    #pragma unroll 1
    for (int mm = 0; mm < 2; ++mm) {
        if (half == mm) {
            #pragma unroll
            for (int j = 0; j < 16; ++j) {
                tw[swz(2 * j, col)]     = v[j].x;
                tw[swz(2 * j + 1, col)] = v[j].y;
            }
            GB[wv][mm][col] = g;
        }
        wave_fence();
        v2f gr[16];
        #pragma unroll
        for (int p2 = 0; p2 < 16; ++p2) {
            v2f wr = *(const v2f*)&tw[cbase + 2 * (p2 ^ cm)];
            v2f gg = *(const v2f*)&GB[wv][mm][2 * p2];
            gr[p2] = gg * wr;
        }
        #pragma unroll
        for (int i = 0; i < 16; ++i) {
            const int r = half * 16 + i;
            const int rw = r & 15;
            v2f acc = {0.f, 0.f};
            #pragma unroll
            for (int q = 0; q < 8; ++q) {
                v4f f = *(const v4f*)&tw[r * 32 + 4 * q];
                v2f lo = {f.x, f.y}, hi = {f.z, f.w};
                acc += lo * gr[(2 * q) ^ rw] + hi * gr[(2 * q + 1) ^ rw];
            }
            accR[i] += acc.x + acc.y;
        }
        wave_fence();   // drain reads before the other half re-stages
    }
    #pragma unroll
    for (int i = 0; i < 16; ++i)
        atomicAdd(&ACC[(half * 16 + i) * 32 + col], accR[i]);
    __syncthreads();
    for (int e = tid; e < 1024; e += 256) atomicAdd(ws + WS_GT + e, ACC[e]);
}

// ---------------------------------------------------------------------------
// K4: E = exp(GT); Gn = Gs E Gs; Gh = Gn^{-1/2}; K = Gh*Gs -> ws[WS_K].
// ---------------------------------------------------------------------------
__global__ __launch_bounds__(64) void k_karcher(float* __restrict__ ws) {
    __shared__ float LA[32 * SP];
    __shared__ float LB[32 * SP];
    const int lane = threadIdx.x;
    const int col  = lane & 31;
    const int base = lane & 32;

    for (int e = lane; e < 1024; e += 64)
        LB[(e >> 5) * SP + (e & 31)] = ws[WS_GS + e];
    v2f gsc[16];
    #pragma unroll
    for (int j = 0; j < 16; ++j) {
        gsc[j].x = ws[WS_GS + (2 * j) * 32 + col];
        gsc[j].y = ws[WS_GS + (2 * j + 1) * 32 + col];
    }
    v2f w[16];
    #pragma unroll
    for (int j = 0; j < 16; ++j) {
        w[j].x = ws[WS_GT + (2 * j) * 32 + col];
        w[j].y = ws[WS_GT + (2 * j + 1) * 32 + col];
    }
    v2f cn2 = {0.f, 0.f};
    #pragma unroll
    for (int j = 0; j < 16; ++j) cn2 += w[j] * w[j];
    float fro2 = cn2.x + cn2.y;
    #pragma unroll
    for (int m = 16; m >= 1; m >>= 1) fro2 += __shfl_xor(fro2, m, 64);
    const float shift = __builtin_amdgcn_sqrtf(fro2) + 0.01f;
    #pragma unroll
    for (int j = 0; j < 16; ++j) {
        w[j].x += (2 * j     == col) ? shift : 0.f;
        w[j].y += (2 * j + 1 == col) ? shift : 0.f;
    }
    const float dn = jacobi_fg(w, col, SW_SINGLE);
    put_col(LA, w, col);
    __syncthreads();
    const float lam = __builtin_amdgcn_sqrtf(dn) - shift;
    const float ce  = expf(lam) * __builtin_amdgcn_rcpf(dn);
    v2f ec[16];
    recon_col(LA, ce, col, base, ec);
    __syncthreads();
    put_col(LA, ec, col);
    __syncthreads();
    v2f u[16], gn[16];
    colmm(LA, gsc, u);
    colmm(LB, u, gn);
    const float dn2 = jacobi_fg(gn, col, SW_SINGLE);
    __syncthreads();
    put_col(LA, gn, col);
    __syncthreads();
    const float lam2 = __builtin_amdgcn_sqrtf(dn2);
    const float ch   = __builtin_amdgcn_rsqf(lam2) * __builtin_amdgcn_rcpf(dn2);
    v2f gh[16];
    recon_col(LA, ch, col, base, gh);
    __syncthreads();
    put_col(LA, gh, col);
    __syncthreads();
    v2f kc[16];
    colmm(LA, gsc, kc);
    #pragma unroll
    for (int j = 0; j < 16; ++j) {
        ws[WS_K + (2 * j) * 32 + col]     = kc[j].x;
        ws[WS_K + (2 * j + 1) * 32 + col] = kc[j].y;
    }
}

// ---------------------------------------------------------------------------
// K5 (pass 2, warm): F = K * W1 * diag(lam1^{-1/2}); 3-sweep Jacobi;
// var += sum(log lam)^2; W2 -> wbuf. lam_k = ||f_k||^2.
// ---------------------------------------------------------------------------
__global__ __launch_bounds__(256, 6) void k_batch_warm(float* __restrict__ wbuf,
                                                       float* __restrict__ ws) {
    __shared__ float KL[1024];
    __shared__ float VARB;
    const int tid = threadIdx.x;
    if (tid == 0) VARB = 0.f;
    for (int e = tid; e < 1024; e += 256) KL[e] = ws[WS_K + e];
    __syncthreads();

    const int lane = tid & 63;
    const int col  = lane & 31;
    const int matl = (tid >> 6) * 2 + (lane >> 5);
    const size_t gm = (size_t)blockIdx.x * 8 + matl;
    float* wp = wbuf + gm * 1024 + col;

    float w1[32];
    #pragma unroll
    for (int i = 0; i < 32; ++i) w1[i] = wp[i * 32];
    float nn = 0.f;
    #pragma unroll
    for (int i = 0; i < 32; ++i) nn = __builtin_fmaf(w1[i], w1[i], nn);
    const float s = __builtin_amdgcn_rsqf(__builtin_amdgcn_sqrtf(nn));
    v2f w1s[16];
    #pragma unroll
    for (int j = 0; j < 16; ++j) { w1s[j].x = w1[2 * j] * s; w1s[j].y = w1[2 * j + 1] * s; }

    v2f v[16];
    #pragma unroll
    for (int i = 0; i < 32; ++i) {
        v2f acc = {0.f, 0.f};
        #pragma unroll
        for (int q = 0; q < 8; ++q) {
            v4f f = *(const v4f*)&KL[i * 32 + 4 * q];
            v2f lo = {f.x, f.y}, hi = {f.z, f.w};
            acc += lo * w1s[2 * q] + hi * w1s[2 * q + 1];
        }
        float fi = acc.x + acc.y;
        if (i & 1) v[i >> 1].y = fi; else v[i >> 1].x = fi;
    }

    const float dn = jacobi_fg(v, col, SW2);   // = lambda (factor init)
    const float lg = logf(dn);
    float contrib = lg * lg;
    #pragma unroll
    for (int m = 32; m >= 1; m >>= 1) contrib += __shfl_xor(contrib, m, 64);
    if (lane == 0) atomicAdd(&VARB, contrib);

    #pragma unroll
    for (int j = 0; j < 16; ++j) {
        wp[(2 * j) * 32]     = v[j].x;
        wp[(2 * j + 1) * 32] = v[j].y;
    }
    __syncthreads();
    if (tid == 0) atomicAdd(ws + WS_VAR, VARB * (1.0f / (float)NMAT));
}

// ---------------------------------------------------------------------------
// K6: p = sqrt(1/(var+eps)); Y = C W2 diag(lam^{(p-1)/2}); out = Y Y^T.
// ---------------------------------------------------------------------------
__global__ __launch_bounds__(256, 4) void k_final(float* __restrict__ out,
                                                  const float* __restrict__ ws) {
    __shared__ float YL[8 * 1024];
    __shared__ float CL[1024];
    const int tid = threadIdx.x;
    for (int e = tid; e < 1024; e += 256) CL[e] = ws[WS_C + e];
    __syncthreads();

    const int lane = tid & 63;
    const int col  = lane & 31;
    const int matl = (tid >> 6) * 2 + (lane >> 5);
    const size_t gm = (size_t)blockIdx.x * 8 + matl;
    float* Ym = YL + matl * 1024;
    const int cm = col & 15, cbase = col * 32;

    const float var = ws[WS_VAR];
    const float p = sqrtf(1.0f / (var + 1e-5f));

    float w[32];
    #pragma unroll
    for (int i = 0; i < 32; ++i) w[i] = out[gm * 1024 + i * 32 + col];
    float d2 = 0.f;
    #pragma unroll
    for (int i = 0; i < 32; ++i) d2 = __builtin_fmaf(w[i], w[i], d2);
    const float dj = exp2f(log2f(d2) * 0.5f * (p - 1.0f));
    v2f wv2[16];
    #pragma unroll
    for (int j = 0; j < 16; ++j) { wv2[j].x = w[2 * j]; wv2[j].y = w[2 * j + 1]; }

    const int cp = col >> 1, cb = col & 1;
    #pragma unroll
    for (int i = 0; i < 32; ++i) {
        v2f acc = {0.f, 0.f};
        #pragma unroll
        for (int j = 0; j < 16; ++j)
            acc += *(const v2f*)&CL[i * 32 + 2 * j] * wv2[j];
        Ym[i * 32 + 2 * (cp ^ (i & 15)) + cb] = (acc.x + acc.y) * dj;
    }
    __syncthreads();

    v2f yr2[16];
    #pragma unroll
    for (int pp = 0; pp < 16; ++pp) yr2[pp] = *(const v2f*)&YL[matl * 1024 + cbase + 2 * (pp ^ cm)];
    #pragma unroll
    for (int i = 0; i < 32; ++i) {
        v2f acc = {0.f, 0.f};
        #pragma unroll
        for (int s2 = 0; s2 < 16; ++s2)
            acc += *(const v2f*)&Ym[i * 32 + 2 * s2] * yr2[s2 ^ (i & 15)];
        out[gm * 1024 + i * 32 + col] = acc.x + acc.y;
    }
}

extern "C" void kernel_launch(void* const* d_in, const int* in_sizes, int n_in,
                              void* d_out, int out_size, void* d_ws, size_t ws_size,
                              hipStream_t stream) {
    const float* X = (const float*)d_in[0];
    const float* R = (const float*)d_in[1];
    const float* B = (const float*)d_in[2];
    float* out = (float*)d_out;
    float* ws  = (float*)d_ws;

    hipMemsetAsync(d_ws, 0, WS_TOTAL * sizeof(float), stream);
    k_mean<<<NMAT / 64, 256, 0, stream>>>(X, ws);
    k_small_prep<<<2, 64, 0, stream>>>(R, B, ws);
    k_batch_log<<<NMAT / 8, 256, 0, stream>>>(X, out, ws);
    k_karcher<<<1, 64, 0, stream>>>(ws);
    k_batch_warm<<<NMAT / 8, 256, 0, stream>>>(out, ws);
    k_final<<<NMAT / 8, 256, 0, stream>>>(out, ws);
}

// Round 7
// 1881.740 us; speedup vs baseline: 1.4727x; 1.1316x over previous
//
#include <hip/hip_runtime.h>
#include <math.h>

typedef float v2f __attribute__((ext_vector_type(2)));
typedef float v4f __attribute__((ext_vector_type(4)));

#define NMAT 32768
#define SW1 4          // pass-1 sweeps (sets Xw-proxy accuracy; keep 4)
#define SW2 2          // pass-2 sweeps (warm start eps0 ~2e-2 -> <1e-6)
#define SW_SINGLE 10   // single-matrix eigs
#define SP 34          // padded row stride for single-wave LDS matrices

// workspace float offsets
#define WS_G    0
#define WS_GS   1024
#define WS_GIS  2048
#define WS_GT   3072
#define WS_K    4096
#define WS_C    5120
#define WS_S1   6144
#define WS_S2   6145
#define WS_P    6146
#define WS_TOTAL 6400

// pair-swizzled 32x32 tile: element (r,c) at r*32 + 2*((c>>1)^(r&15)) + (c&1).
__device__ __forceinline__ int swz(int r, int c) {
    return r * 32 + 2 * ((c >> 1) ^ (r & 15)) + (c & 1);
}

// same-wave LDS write->read visibility (no block barrier needed)
__device__ __forceinline__ void wave_fence() {
    asm volatile("s_waitcnt lgkmcnt(0)" ::: "memory");
}

// xor-shuffle: CTRL!=0 -> VALU DPP quad_perm (valid for m in {1,2,3});
// CTRL==0 -> DS shuffle. Moves 3 rounds/sweep off the saturated DS pipe.
template<int CTRL>
__device__ __forceinline__ float xsh(float x, int m) {
    if constexpr (CTRL != 0) {
        return __int_as_float(__builtin_amdgcn_update_dpp(
            __float_as_int(x), __float_as_int(x), CTRL, 0xF, 0xF, true));
    } else {
        return __shfl_xor(x, m, 64);
    }
}

// One fast-Givens Jacobi round against partner col^m.
template<int CTRL>
__device__ __forceinline__ void jac_round(v2f (&v)[16], int col, int m,
                                          float& dn, float& sc, float& rsc) {
    const float dnq = xsh<CTRL>(dn, m);
    const float dq  = xsh<CTRL>(sc, m);
    v2f o[16];
    #pragma unroll
    for (int j = 0; j < 16; ++j) {
        o[j].x = xsh<CTRL>(v[j].x, m);
        o[j].y = xsh<CTRL>(v[j].y, m);
    }
    v2f p0 = v[0] * o[0], p1 = v[1] * o[1], p2 = v[2] * o[2], p3 = v[3] * o[3];
    #pragma unroll
    for (int j = 4; j < 16; j += 4) {
        p0 += v[j] * o[j];     p1 += v[j + 1] * o[j + 1];
        p2 += v[j + 2] * o[j + 2]; p3 += v[j + 3] * o[j + 3];
    }
    v2f pt = (p0 + p1) + (p2 + p3);
    const float raw = pt.x + pt.y;
    const bool  isp = col < (col ^ m);
    const float apq = (sc * dq) * raw;
    const float b   = apq + apq;
    const float d   = isp ? (dnq - dn) : (dn - dnq);   // aqq - app
    const float r2  = __builtin_fmaf(d, d, b * b);
    const float sr  = __builtin_amdgcn_sqrtf(r2);
    const float u   = fmaxf(fabsf(d) + sr, 1e-30f);
    const float t   = (d < 0.f ? -b : b) * __builtin_amdgcn_rcpf(u);
    const float s1  = __builtin_fmaf(t, t, 1.f);
    const float c   = __builtin_amdgcn_rsqf(s1);
    const float gam = t * (dq * rsc);
    const float gs  = isp ? -gam : gam;
    const v2f gs2 = {gs, gs};
    #pragma unroll
    for (int j = 0; j < 16; ++j) v[j] += gs2 * o[j];
    sc *= c; rsc *= c * s1;                     // c*s1 = 1/c
    dn = __builtin_fmaf(isp ? -t : t, apq, dn);
}

// ---------------------------------------------------------------------------
// One-sided Jacobi, fast-Givens form, XOR tournament (m=1..3 on VALU DPP).
// Lane owns one column in 16 v2f regs. Returns final true squared norm.
// ---------------------------------------------------------------------------
__device__ __forceinline__ float jacobi_fg(v2f (&v)[16], int col, int sweeps) {
    float dn = 0.f;
    #pragma unroll 1
    for (int sweep = 0; sweep < sweeps; ++sweep) {
        {
            v2f n0 = v[0] * v[0], n1 = v[1] * v[1], n2 = v[2] * v[2], n3 = v[3] * v[3];
            #pragma unroll
            for (int j = 4; j < 16; j += 4) {
                n0 += v[j] * v[j];     n1 += v[j + 1] * v[j + 1];
                n2 += v[j + 2] * v[j + 2]; n3 += v[j + 3] * v[j + 3];
            }
            v2f nt = (n0 + n1) + (n2 + n3);
            dn = nt.x + nt.y;
        }
        float sc = 1.f, rsc = 1.f;
        jac_round<0xB1>(v, col, 1, dn, sc, rsc);   // quad_perm [1,0,3,2]
        jac_round<0x4E>(v, col, 2, dn, sc, rsc);   // quad_perm [2,3,0,1]
        jac_round<0x1B>(v, col, 3, dn, sc, rsc);   // quad_perm [3,2,1,0]
        #pragma unroll 1
        for (int m = 4; m < 32; ++m) jac_round<0>(v, col, m, dn, sc, rsc);
        const v2f s2 = {sc, sc};
        #pragma unroll
        for (int j = 0; j < 16; ++j) v[j] *= s2;
    }
    v2f n0 = v[0] * v[0], n1 = v[1] * v[1], n2 = v[2] * v[2], n3 = v[3] * v[3];
    #pragma unroll
    for (int j = 4; j < 16; j += 4) {
        n0 += v[j] * v[j];     n1 += v[j + 1] * v[j + 1];
        n2 += v[j + 2] * v[j + 2]; n3 += v[j + 3] * v[j + 3];
    }
    v2f nt = (n0 + n1) + (n2 + n3);
    return nt.x + nt.y;
}

// ---------------------------------------------------------------------------
// Single-wave helpers
// ---------------------------------------------------------------------------
__device__ __forceinline__ void put_col(float* L, const v2f (&w)[16], int col) {
    #pragma unroll
    for (int j = 0; j < 16; ++j) {
        L[(2 * j) * SP + col]     = w[j].x;
        L[(2 * j + 1) * SP + col] = w[j].y;
    }
}

__device__ __forceinline__ void colmm(const float* L, const v2f (&y)[16], v2f (&z)[16]) {
    #pragma unroll
    for (int i = 0; i < 32; ++i) {
        v2f acc = {0.f, 0.f};
        #pragma unroll
        for (int q = 0; q < 16; ++q) {
            v2f mm = *(const v2f*)&L[i * SP + 2 * q];
            acc += mm * y[q];
        }
        float zi = acc.x + acc.y;
        if (i & 1) z[i >> 1].y = zi; else z[i >> 1].x = zi;
    }
}

__device__ __forceinline__ void recon_col(const float* LW, float coef, int col,
                                          int base, v2f (&z)[16]) {
    float rv[32];
    #pragma unroll
    for (int k = 0; k < 32; ++k) rv[k] = LW[col * SP + k];
    v2f y[16];
    #pragma unroll
    for (int q = 0; q < 16; ++q) {
        y[q].x = __shfl(coef, base | (2 * q), 64)     * rv[2 * q];
        y[q].y = __shfl(coef, base | (2 * q + 1), 64) * rv[2 * q + 1];
    }
    colmm(LW, y, z);
}

// ---------------------------------------------------------------------------
// K1: arithmetic mean -> ws[WS_G]
// ---------------------------------------------------------------------------
__global__ __launch_bounds__(256) void k_mean(const float* __restrict__ X,
                                              float* __restrict__ ws) {
    const int t = threadIdx.x;
    const size_t base = (size_t)blockIdx.x * 64 * 1024;
    float4 a = {0.f, 0.f, 0.f, 0.f};
    for (int m = 0; m < 64; ++m) {
        float4 f = *(const float4*)&X[base + (size_t)m * 1024 + t * 4];
        a.x += f.x; a.y += f.y; a.z += f.z; a.w += f.w;
    }
    const float s = 1.0f / (float)NMAT;
    atomicAdd(ws + WS_G + 4 * t + 0, a.x * s);
    atomicAdd(ws + WS_G + 4 * t + 1, a.y * s);
    atomicAdd(ws + WS_G + 4 * t + 2, a.z * s);
    atomicAdd(ws + WS_G + 4 * t + 3, a.w * s);
}

// ---------------------------------------------------------------------------
// K2: block 0: eig(G) -> Gs, Gis.  block 1: eig(B) -> C = B^{1/2} R.
// ---------------------------------------------------------------------------
__global__ __launch_bounds__(64) void k_small_prep(const float* __restrict__ R,
                                                   const float* __restrict__ B,
                                                   float* __restrict__ ws) {
    __shared__ float LW[32 * SP];
    const int lane = threadIdx.x;
    const int col  = lane & 31;
    const int base = lane & 32;
    if (blockIdx.x == 0) {
        v2f w[16];
        #pragma unroll
        for (int j = 0; j < 16; ++j) {
            w[j].x = ws[WS_G + (2 * j) * 32 + col];
            w[j].y = ws[WS_G + (2 * j + 1) * 32 + col];
        }
        const float dn = jacobi_fg(w, col, SW_SINGLE);   // dn = lam^2
        put_col(LW, w, col);
        __syncthreads();
        const float lam = __builtin_amdgcn_sqrtf(dn);
        const float cs  = __builtin_amdgcn_sqrtf(lam) * __builtin_amdgcn_rcpf(dn);
        const float cis = __builtin_amdgcn_rsqf(lam)  * __builtin_amdgcn_rcpf(dn);
        v2f z[16];
        recon_col(LW, cs, col, base, z);    // Gs
        #pragma unroll
        for (int j = 0; j < 16; ++j) {
            ws[WS_GS + (2 * j) * 32 + col]     = z[j].x;
            ws[WS_GS + (2 * j + 1) * 32 + col] = z[j].y;
        }
        recon_col(LW, cis, col, base, z);   // Gis
        #pragma unroll
        for (int j = 0; j < 16; ++j) {
            ws[WS_GIS + (2 * j) * 32 + col]     = z[j].x;
            ws[WS_GIS + (2 * j + 1) * 32 + col] = z[j].y;
        }
    } else {
        v2f w[16];
        #pragma unroll
        for (int j = 0; j < 16; ++j) {
            w[j].x = B[(2 * j) * 32 + col];
            w[j].y = B[(2 * j + 1) * 32 + col];
        }
        const float dn = jacobi_fg(w, col, SW_SINGLE);
        put_col(LW, w, col);
        __syncthreads();
        const float lam = __builtin_amdgcn_sqrtf(dn);
        const float cbs = __builtin_amdgcn_sqrtf(lam) * __builtin_amdgcn_rcpf(dn);
        v2f bs[16];
        recon_col(LW, cbs, col, base, bs);  // Bs = B^{1/2}
        __syncthreads();
        put_col(LW, bs, col);               // LW <- Bs
        __syncthreads();
        v2f r[16];
        #pragma unroll
        for (int j = 0; j < 16; ++j) {
            r[j].x = R[(2 * j) * 32 + col];
            r[j].y = R[(2 * j + 1) * 32 + col];
        }
        v2f c[16];
        colmm(LW, r, c);                    // C = Bs * R
        #pragma unroll
        for (int j = 0; j < 16; ++j) {
            ws[WS_C + (2 * j) * 32 + col]     = c[j].x;
            ws[WS_C + (2 * j + 1) * 32 + col] = c[j].y;
        }
    }
}

// ---------------------------------------------------------------------------
// K3 (pass 1, fused): M = Gis X Gis; Jacobi; W1 -> w1out;
// GT += mean_m W diag(log(lam)/lam^2) W^T; S1 += mean sum log(lam);
// S2 += mean sum log^2(lam)   (var computed from S1,S2 in k_karcher).
// ---------------------------------------------------------------------------
__global__ __launch_bounds__(256, 6) void k_batch_log(const float* __restrict__ X,
                                                      float* __restrict__ w1out,
                                                      float* __restrict__ ws) {
    __shared__ float HL[1024];       // Gis, pair-swizzled
    __shared__ float TW[4][1024];    // per-wave take-turns W tile
    __shared__ float GB[4][2][32];   // per-wave, per-half g coefficients
    __shared__ float ACC[1024];      // block GT accumulator
    __shared__ float S1B, S2B;
    const int tid = threadIdx.x;
    if (tid == 0) { S1B = 0.f; S2B = 0.f; }
    for (int e = tid; e < 1024; e += 256) {
        int r = e >> 5, c = e & 31;
        HL[swz(r, c)] = ws[WS_GIS + e];
        ACC[e] = 0.f;
    }
    __syncthreads();

    const int lane = tid & 63;
    const int col  = lane & 31;
    const int half = lane >> 5;
    const int wv   = tid >> 6;
    const size_t gm = (size_t)blockIdx.x * 8 + wv * 2 + half;
    const float* Xm = X + gm * 1024;
    const int cm = col & 15, cbase = col * 32;
    float* tw = TW[wv];

    v2f h2[16];
    #pragma unroll
    for (int p = 0; p < 16; ++p) h2[p] = *(const v2f*)&HL[cbase + 2 * (p ^ cm)];

    v2f t2[16];
    #pragma unroll
    for (int i = 0; i < 32; ++i) {
        const float4* row = (const float4*)(Xm + i * 32);
        v2f acc = {0.f, 0.f};
        #pragma unroll
        for (int q = 0; q < 8; ++q) {
            float4 f = row[q];
            v2f lo = {f.x, f.y}, hi = {f.z, f.w};
            acc += lo * h2[2 * q] + hi * h2[2 * q + 1];
        }
        float ti = acc.x + acc.y;
        if (i & 1) t2[i >> 1].y = ti; else t2[i >> 1].x = ti;
    }
    v2f v[16];
    #pragma unroll
    for (int i = 0; i < 32; ++i) {
        v2f acc = {0.f, 0.f};
        const int twi = i & 15;
        #pragma unroll
        for (int q = 0; q < 8; ++q) {
            v4f f = *(const v4f*)&HL[i * 32 + 4 * q];
            v2f lo = {f.x, f.y}, hi = {f.z, f.w};
            acc += lo * t2[(2 * q) ^ twi] + hi * t2[(2 * q + 1) ^ twi];
        }
        float wi = acc.x + acc.y;
        if (i & 1) v[i >> 1].y = wi; else v[i >> 1].x = wi;
    }

    const float dn = jacobi_fg(v, col, SW1);

    // W1 to global (warm-start for pass 2)
    float* outp = w1out + gm * 1024 + col;
    #pragma unroll
    for (int j = 0; j < 16; ++j) {
        outp[(2 * j) * 32]     = v[j].x;
        outp[(2 * j + 1) * 32] = v[j].y;
    }

    // log-eigen stats: ls = log(sigma); g for GT recon
    const float ls = 0.5f * logf(dn);
    const float g  = ls * __builtin_amdgcn_rcpf(dn) * (1.0f / (float)NMAT);
    {
        float s1 = ls, s2 = ls * ls;
        #pragma unroll
        for (int m = 32; m >= 1; m >>= 1) {
            s1 += __shfl_xor(s1, m, 64);
            s2 += __shfl_xor(s2, m, 64);
        }
        if (lane == 0) { atomicAdd(&S1B, s1); atomicAdd(&S2B, s2); }
    }

    float accR[16];
    #pragma unroll
    for (int i = 0; i < 16; ++i) accR[i] = 0.f;

    #pragma unroll 1
    for (int mm = 0; mm < 2; ++mm) {
        if (half == mm) {
            #pragma unroll
            for (int j = 0; j < 16; ++j) {
                tw[swz(2 * j, col)]     = v[j].x;
                tw[swz(2 * j + 1, col)] = v[j].y;
            }
            GB[wv][mm][col] = g;
        }
        wave_fence();
        v2f gr[16];
        #pragma unroll
        for (int p2 = 0; p2 < 16; ++p2) {
            v2f wr = *(const v2f*)&tw[cbase + 2 * (p2 ^ cm)];
            v2f gg = *(const v2f*)&GB[wv][mm][2 * p2];
            gr[p2] = gg * wr;
        }
        #pragma unroll
        for (int i = 0; i < 16; ++i) {
            const int r = half * 16 + i;
            const int rw = r & 15;
            v2f acc = {0.f, 0.f};
            #pragma unroll
            for (int q = 0; q < 8; ++q) {
                v4f f = *(const v4f*)&tw[r * 32 + 4 * q];
                v2f lo = {f.x, f.y}, hi = {f.z, f.w};
                acc += lo * gr[(2 * q) ^ rw] + hi * gr[(2 * q + 1) ^ rw];
            }
            accR[i] += acc.x + acc.y;
        }
        wave_fence();   // drain reads before the other half re-stages
    }
    #pragma unroll
    for (int i = 0; i < 16; ++i)
        atomicAdd(&ACC[(half * 16 + i) * 32 + col], accR[i]);
    __syncthreads();
    for (int e = tid; e < 1024; e += 256) atomicAdd(ws + WS_GT + e, ACC[e]);
    if (tid == 0) {
        atomicAdd(ws + WS_S1, S1B * (1.0f / (float)NMAT));
        atomicAdd(ws + WS_S2, S2B * (1.0f / (float)NMAT));
    }
}

// ---------------------------------------------------------------------------
// K4: E = exp(GT); Gn = Gs E Gs; Gh = Gn^{-1/2}; K = Gh*Gs -> ws[WS_K].
// Also: var = S2 - S1^2/32 (GT ~ cI + traceless fluct); p -> ws[WS_P].
// ---------------------------------------------------------------------------
__global__ __launch_bounds__(64) void k_karcher(float* __restrict__ ws) {
    __shared__ float LA[32 * SP];
    __shared__ float LB[32 * SP];
    const int lane = threadIdx.x;
    const int col  = lane & 31;
    const int base = lane & 32;

    for (int e = lane; e < 1024; e += 64)
        LB[(e >> 5) * SP + (e & 31)] = ws[WS_GS + e];
    v2f gsc[16];
    #pragma unroll
    for (int j = 0; j < 16; ++j) {
        gsc[j].x = ws[WS_GS + (2 * j) * 32 + col];
        gsc[j].y = ws[WS_GS + (2 * j + 1) * 32 + col];
    }
    v2f w[16];
    #pragma unroll
    for (int j = 0; j < 16; ++j) {
        w[j].x = ws[WS_GT + (2 * j) * 32 + col];
        w[j].y = ws[WS_GT + (2 * j + 1) * 32 + col];
    }
    v2f cn2 = {0.f, 0.f};
    #pragma unroll
    for (int j = 0; j < 16; ++j) cn2 += w[j] * w[j];
    float fro2 = cn2.x + cn2.y;
    #pragma unroll
    for (int m = 16; m >= 1; m >>= 1) fro2 += __shfl_xor(fro2, m, 64);
    const float shift = __builtin_amdgcn_sqrtf(fro2) + 0.01f;
    #pragma unroll
    for (int j = 0; j < 16; ++j) {
        w[j].x += (2 * j     == col) ? shift : 0.f;
        w[j].y += (2 * j + 1 == col) ? shift : 0.f;
    }
    const float dn = jacobi_fg(w, col, SW_SINGLE);
    put_col(LA, w, col);
    __syncthreads();
    const float lam = __builtin_amdgcn_sqrtf(dn) - shift;
    const float ce  = expf(lam) * __builtin_amdgcn_rcpf(dn);
    v2f ec[16];
    recon_col(LA, ce, col, base, ec);
    __syncthreads();
    put_col(LA, ec, col);
    __syncthreads();
    v2f u[16], gn[16];
    colmm(LA, gsc, u);
    colmm(LB, u, gn);
    const float dn2 = jacobi_fg(gn, col, SW_SINGLE);
    __syncthreads();
    put_col(LA, gn, col);
    __syncthreads();
    const float lam2 = __builtin_amdgcn_sqrtf(dn2);
    const float ch   = __builtin_amdgcn_rsqf(lam2) * __builtin_amdgcn_rcpf(dn2);
    v2f gh[16];
    recon_col(LA, ch, col, base, gh);
    __syncthreads();
    put_col(LA, gh, col);
    __syncthreads();
    v2f kc[16];
    colmm(LA, gsc, kc);
    #pragma unroll
    for (int j = 0; j < 16; ++j) {
        ws[WS_K + (2 * j) * 32 + col]     = kc[j].x;
        ws[WS_K + (2 * j + 1) * 32 + col] = kc[j].y;
    }
    if (lane == 0) {
        const float S1  = ws[WS_S1];
        const float S2  = ws[WS_S2];
        const float var = S2 - S1 * S1 * 0.03125f;   // S2 - S1^2/32
        ws[WS_P] = __builtin_amdgcn_rsqf(var + 1e-5f);
    }
}

// ---------------------------------------------------------------------------
// K5 (fused warm+final): F = K W1 diag(lam1^{-1/2}); 2-sweep Jacobi -> lam;
// Y = C W2 diag(lam^{(p-1)/2}); out = Y Y^T  (take-turns per-wave tile).
// ---------------------------------------------------------------------------
__global__ __launch_bounds__(256, 6) void k_fused(float* __restrict__ out,
                                                  const float* __restrict__ ws) {
    __shared__ float KL[1024];       // K, natural (broadcast rows)
    __shared__ float CL[1024];       // C, natural (broadcast rows)
    __shared__ float TW[4][1024];    // per-wave take-turns Y tile
    const int tid = threadIdx.x;
    for (int e = tid; e < 1024; e += 256) {
        KL[e] = ws[WS_K + e];
        CL[e] = ws[WS_C + e];
    }
    __syncthreads();

    const int lane = tid & 63;
    const int col  = lane & 31;
    const int half = lane >> 5;
    const int wv   = tid >> 6;
    const size_t gmbase = (size_t)blockIdx.x * 8 + wv * 2;
    const size_t gm = gmbase + half;
    const int cm = col & 15, cbase = col * 32;
    float* tw = TW[wv];

    const float p = ws[WS_P];

    // own W1 column (row-coalesced)
    const float* wp = out + gm * 1024 + col;
    float w1[32];
    #pragma unroll
    for (int i = 0; i < 32; ++i) w1[i] = wp[i * 32];
    float nn = 0.f;
    #pragma unroll
    for (int i = 0; i < 32; ++i) nn = __builtin_fmaf(w1[i], w1[i], nn);
    const float s = __builtin_amdgcn_rsqf(__builtin_amdgcn_sqrtf(nn));  // lam1^{-1/2}
    v2f w1s[16];
    #pragma unroll
    for (int j = 0; j < 16; ++j) { w1s[j].x = w1[2 * j] * s; w1s[j].y = w1[2 * j + 1] * s; }

    // F col = K * w1s
    v2f v[16];
    #pragma unroll
    for (int i = 0; i < 32; ++i) {
        v2f acc = {0.f, 0.f};
        #pragma unroll
        for (int q = 0; q < 8; ++q) {
            v4f f = *(const v4f*)&KL[i * 32 + 4 * q];
            v2f lo = {f.x, f.y}, hi = {f.z, f.w};
            acc += lo * w1s[2 * q] + hi * w1s[2 * q + 1];
        }
        float fi = acc.x + acc.y;
        if (i & 1) v[i >> 1].y = fi; else v[i >> 1].x = fi;
    }

    const float dn = jacobi_fg(v, col, SW2);   // = lambda (factor init)
    const float dj = exp2f(log2f(dn) * 0.5f * (p - 1.0f));  // lam^{(p-1)/2}

    v2f yv[16];
    #pragma unroll
    for (int j = 0; j < 16; ++j) { yv[j].x = v[j].x * dj; yv[j].y = v[j].y * dj; }

    // y = C * yv  (full Y column)
    float y[32];
    #pragma unroll
    for (int i = 0; i < 32; ++i) {
        v2f acc = {0.f, 0.f};
        #pragma unroll
        for (int q = 0; q < 8; ++q) {
            v4f f = *(const v4f*)&CL[i * 32 + 4 * q];
            v2f lo = {f.x, f.y}, hi = {f.z, f.w};
            acc += lo * yv[2 * q] + hi * yv[2 * q + 1];
        }
        y[i] = acc.x + acc.y;
    }

    // out = Y Y^T via take-turns tile (half-waves split output rows)
    #pragma unroll 1
    for (int mm = 0; mm < 2; ++mm) {
        if (half == mm) {
            #pragma unroll
            for (int j = 0; j < 16; ++j) {
                tw[swz(2 * j, col)]     = y[2 * j];
                tw[swz(2 * j + 1, col)] = y[2 * j + 1];
            }
        }
        wave_fence();
        v2f yc[16];
        #pragma unroll
        for (int p2 = 0; p2 < 16; ++p2)
            yc[p2] = *(const v2f*)&tw[cbase + 2 * (p2 ^ cm)];
        const size_t gmo = gmbase + mm;
        #pragma unroll
        for (int i = 0; i < 16; ++i) {
            const int r = half * 16 + i;
            const int rw = r & 15;
            v2f acc = {0.f, 0.f};
            #pragma unroll
            for (int q = 0; q < 8; ++q) {
                v4f f = *(const v4f*)&tw[r * 32 + 4 * q];
                v2f lo = {f.x, f.y}, hi = {f.z, f.w};
                acc += lo * yc[(2 * q) ^ rw] + hi * yc[(2 * q + 1) ^ rw];
            }
            out[gmo * 1024 + r * 32 + col] = acc.x + acc.y;
        }
        wave_fence();
    }
}

extern "C" void kernel_launch(void* const* d_in, const int* in_sizes, int n_in,
                              void* d_out, int out_size, void* d_ws, size_t ws_size,
                              hipStream_t stream) {
    const float* X = (const float*)d_in[0];
    const float* R = (const float*)d_in[1];
    const float* B = (const float*)d_in[2];
    float* out = (float*)d_out;
    float* ws  = (float*)d_ws;

    hipMemsetAsync(d_ws, 0, WS_TOTAL * sizeof(float), stream);
    k_mean<<<NMAT / 64, 256, 0, stream>>>(X, ws);
    k_small_prep<<<2, 64, 0, stream>>>(R, B, ws);
    k_batch_log<<<NMAT / 8, 256, 0, stream>>>(X, out, ws);
    k_karcher<<<1, 64, 0, stream>>>(ws);
    k_fused<<<NMAT / 8, 256, 0, stream>>>(out, ws);
}